// Round 6
// baseline (261.662 us; speedup 1.0000x reference)
//
#include <hip/hip_runtime.h>
#include <hip/hip_bf16.h>
#include <math.h>

typedef short s16x8 __attribute__((ext_vector_type(8)));
typedef float f32x4 __attribute__((ext_vector_type(4)));

__device__ inline ushort f2bf(float f) {
  unsigned u = __float_as_uint(f);
  u = (u + 0x7FFF + ((u >> 16) & 1)) >> 16;
  return (ushort)u;
}
__device__ inline float bf2f(ushort u) {
  return __uint_as_float(((unsigned)u) << 16);
}
// packed f32x2 -> bf16x2 RNE (bit-identical to f2bf pair)
__device__ inline unsigned pkbf(float a, float b) {
  __hip_bfloat162 h = __float22bfloat162_rn(make_float2(a, b));
  return *(unsigned*)&h;
}
// bf16 pair unpack from a dword: low half / high half (bit-identical to bf2f)
__device__ inline float bflo(unsigned u) { return __uint_as_float(u << 16); }
__device__ inline float bfhi(unsigned u) { return __uint_as_float(u & 0xffff0000u); }
// fast activations: v_exp_f32 + v_rcp_f32; saturate correctly at +/-inf.
__device__ inline float fast_tanh(float v) {
  float e = __builtin_amdgcn_exp2f(v * 2.8853900817779268f);   // exp(2v)
  return 1.f - 2.f * __builtin_amdgcn_rcpf(e + 1.f);
}
__device__ inline float fast_sigmoid(float v) {
  float e = __builtin_amdgcn_exp2f(v * -1.4426950408889634f);  // exp(-v)
  return __builtin_amdgcn_rcpf(1.f + e);
}

// LDS-only barrier: orders ds ops across waves WITHOUT draining vmcnt (so prefetched
// global loads stay in flight across phase boundaries).
#define LDS_BARRIER()                                          \
  do {                                                         \
    asm volatile("s_waitcnt lgkmcnt(0)" ::: "memory");         \
    __builtin_amdgcn_s_barrier();                              \
  } while (0)

// ---- sigma channel permutation -------------------------------------------------------
// c = [rq m q1 q0 r1 r0] -> sigma(c) = [rq q1 q0 m r1 r0].
// The epilogue thread (rowq,quad) owns channels {rq*32+quad*4+r} U {rq*32+16+quad*4+r};
// in sigma-space these 8 channels are CONTIGUOUS -> one uint4 gather per corner.
__device__ inline int sigma(int c) {
  return (c & 0x20) | ((c & 0x0C) << 1) | ((c & 0x10) >> 2) | (c & 3);
}
__device__ inline int sigma_inv(int d) {
  return (d & 0x20) | ((d & 4) << 2) | ((d & 0x18) >> 1) | (d & 3);
}

// ---- PERMUTED head-row space (640 rows):
//   g in [0,18): off | [18,27): mod | [27,64): pad | [64,640): col j=g-64=k*64+c
//     source col channel cc = c*9+k.
// ---- K1: fused 1x1 conv -> fusedt[pix][64] bf16 + xtb (sigma-space) transpose,
//      PLUS weight packing (former k_merge) on blocks >= 1024 -------------------------
// Wpk[og 5][ks 18][ocq 2][mi 4][lane 64][e 8]; W2pk[ks 18][mi 4][lane 64][e 8].
__global__ __launch_bounds__(256) void k_fused(
    const float* __restrict__ x, const float* __restrict__ ref,
    const float* __restrict__ wcd, const float* __restrict__ bcd,
    const float* __restrict__ wp, const float* __restrict__ bp,
    const float* __restrict__ wm, const float* __restrict__ bm,
    const float* __restrict__ wc, const float* __restrict__ bc,
    const float* __restrict__ wconv,
    ushort* __restrict__ fusedt, ushort* __restrict__ xtb,
    ushort* __restrict__ Wpk, float* __restrict__ Bc, ushort* __restrict__ W2pk) {
  __shared__ float sw[128 * 64];
  __shared__ float sx[64][65];
  __shared__ float sb[64];

  if (blockIdx.x >= 1024) {
    // ---- weight-packing blocks (former k_merge), 1440 blocks ----
    int i = (blockIdx.x - 1024) * 256 + threadIdx.x;
    if (i < 368640) {
      int e = i & 7, lane = (i >> 3) & 63, mi = (i >> 9) & 3, ocq = (i >> 11) & 1;
      int hi = i >> 12;                 // 0..89
      int ks = hi % 18, og = hi / 18;
      int g = og * 128 + ocq * 64 + mi * 16 + (lane & 15);
      int ci = ((ks & 1) << 5) + ((lane >> 4) << 3) + e;
      int kk = ks >> 1;
      int col = ci * 9 + kk;
      float v = 0.f;
      if (g < 18)       v = wp[g * 576 + col];
      else if (g < 27)  v = wm[(g - 18) * 576 + col];
      else if (g >= 64) {
        int j = g - 64;
        int cc = (j & 63) * 9 + (j >> 6);
        v = wc[cc * 576 + col];
      }
      Wpk[i] = f2bf(v);
    }
    if (i < 36864) {
      int e = i & 7, lane = (i >> 3) & 63, mi = (i >> 9) & 3, ks = i >> 11;  // 0..17
      int o = mi * 16 + (lane & 15);
      int p = (ks << 5) + ((lane >> 4) << 3) + e;
      int kk2 = p >> 6, d = p & 63;
      int c = sigma_inv(d);            // W2pk K-order lives in sigma-space
      W2pk[i] = f2bf(wconv[o * 576 + c * 9 + kk2]);
    }
    if (i < 640) {
      float bv = 0.f;
      if (i < 18)       bv = bp[i];
      else if (i < 27)  bv = bm[i - 18];
      else if (i >= 64) {
        int j = i - 64;
        bv = bc[(j & 63) * 9 + (j >> 6)];
      }
      Bc[i] = bv;
    }
    return;
  }

  // ---- fused 1x1 conv blocks ----
  const int t = threadIdx.x;
  for (int i = t; i < 128 * 64; i += 256) {
    int ci = i >> 6, o = i & 63;
    sw[i] = wcd[o * 128 + ci];
  }
  if (t < 64) sb[t] = bcd[t];
  const int b = blockIdx.x >> 8, hw0 = (blockIdx.x & 255) << 6;
  for (int i = t; i < 4096; i += 256) {
    int c = i >> 6, hwi = i & 63;
    sx[c][hwi] = x[((size_t)((b << 6) + c) << 14) + hw0 + hwi];
  }
  __syncthreads();

  // xtb[b][hw][sigma-space] bf16 pixel-major -- LINEAR 16B stores.
  // 512 chunks of 8 sigma-elems (2 reps x 256 threads) cover 64 rows x 64 channels.
  // (Round-5 bug: single rep with q4=t&3 covered only sigma-indices 0..31.)
  #pragma unroll
  for (int rep = 0; rep < 2; rep++) {
    int idx = t + (rep << 8);               // 0..511
    int hwi = idx >> 3, q8 = idx & 7;       // row 0..63, chunk 0..7
    uint4 ow;
    unsigned pk[4];
    #pragma unroll
    for (int j = 0; j < 4; j++) {
      int d = (q8 << 3) + (j << 1);         // even sigma index 0..62
      int c = sigma_inv(d);                 // sigma_inv preserves bit0; c even
      pk[j] = pkbf(sx[c][hwi], sx[c + 1][hwi]);
    }
    ow.x = pk[0]; ow.y = pk[1]; ow.z = pk[2]; ow.w = pk[3];
    *(uint4*)(xtb + (((size_t)b << 14) + hw0 + hwi) * 64 + (q8 << 3)) = ow;
  }

  const int pxi = t & 63, oq = t >> 6;      // wave-uniform oq -> LDS broadcast
  const int pix = blockIdx.x * 64 + pxi;
  const float* rb = ref + (((size_t)b << 6) << 14) + hw0 + pxi;

  float4 acc[4];
  #pragma unroll
  for (int q = 0; q < 4; q++)
    acc[q] = *(const float4*)&sb[oq * 16 + 4 * q];

  for (int ci = 0; ci < 64; ci++) {
    float v = sx[ci][pxi];
    const float4* wr = (const float4*)&sw[ci * 64 + oq * 16];
    #pragma unroll
    for (int q = 0; q < 4; q++) {
      float4 w4 = wr[q];
      acc[q].x += w4.x * v; acc[q].y += w4.y * v;
      acc[q].z += w4.z * v; acc[q].w += w4.w * v;
    }
  }
  for (int ci = 0; ci < 64; ci++) {
    float v = rb[(size_t)ci << 14];
    const float4* wr = (const float4*)&sw[(64 + ci) * 64 + oq * 16];
    #pragma unroll
    for (int q = 0; q < 4; q++) {
      float4 w4 = wr[q];
      acc[q].x += w4.x * v; acc[q].y += w4.y * v;
      acc[q].z += w4.z * v; acc[q].w += w4.w * v;
    }
  }
  uint4 o0, o1;
  o0.x = pkbf(acc[0].x, acc[0].y); o0.y = pkbf(acc[0].z, acc[0].w);
  o0.z = pkbf(acc[1].x, acc[1].y); o0.w = pkbf(acc[1].z, acc[1].w);
  o1.x = pkbf(acc[2].x, acc[2].y); o1.y = pkbf(acc[2].z, acc[2].w);
  o1.z = pkbf(acc[3].x, acc[3].y); o1.w = pkbf(acc[3].z, acc[3].w);
  ushort* fb = fusedt + ((size_t)pix << 6) + oq * 16;
  *(uint4*)fb       = o0;
  *(uint4*)(fb + 8) = o1;
}

// ---- K3: FULLY FUSED head-GEMM + sampler + final GEMM, 64-px tiles --------------------
// grid 1024; block 256 = 4 waves; LDS 40,448B -> 4 blocks/CU.
// Round-5/6: COMPRESSED invariant addressing so the live state fits registers and the
// compiler stops rematerializing the address tables per k (round-4 VGPR_Count=64).
// Identities: (x+4)&7 == x^4  =>  slot(ks) = slot(kk) ^ (half*4); r1-r0 = 16 == 0
// (mod 8) => ni0/ni1 share slots. sfo[18][2] -> CR0[9]+CR1[9] + XOR.
__global__ __launch_bounds__(256, 4) void k_all(
    const ushort* __restrict__ Wpk, const ushort* __restrict__ fusedt,
    const float* __restrict__ Bc, const ushort* __restrict__ xtb,
    const ushort* __restrict__ W2pk, float* __restrict__ out) {
  __shared__ __align__(16) ushort sF[3 * 66 * 64];    // 25,344 B
  __shared__ __align__(16) ushort colT[64 * 64];      //  8,192 B
  __shared__ float homT[64 * 27];                     //  6,912 B -> 40,448 B total
  const int t = threadIdx.x;
  const int lane = t & 63, wv = t >> 6;
  const int rowid = blockIdx.x;           // b*256 + h*2 + half
  const int b = rowid >> 8;
  const int rem = rowid & 255;
  const int h = rem >> 1, hf = rem & 1;
  const int w0 = hf << 6;
  const int hw0 = (h << 7) + w0;

  // stage fused rows h-1..h+1, w1 in [0,66) covering gw in [w0-1, w0+64]
  for (int idx = t; idx < 1584; idx += 256) {   // 198 pixels x 8 ci-chunks
    int p = idx >> 3, j = idx & 7;
    int row = p / 66, w1 = p - row * 66;
    int gh = h + row - 1, gw = w0 + w1 - 1;
    uint4 v = make_uint4(0u, 0u, 0u, 0u);
    if (gh >= 0 && gh < 128 && (unsigned)gw < 128u)
      v = *(const uint4*)(fusedt + ((size_t)((b << 14) + (gh << 7) + gw) << 6) + j * 8);
    int slot = (j + w1) & 7;
    *(uint4*)(sF + (p << 6) + slot * 8) = v;
  }

  const int pxq = wv & 1, rowq = wv >> 1;
  const int nif = lane & 15, kb = lane >> 4, quad = lane >> 4;
  const int wlaneoff = lane << 3;                          // element offset in weight row
  const int rfq = __builtin_amdgcn_readfirstlane(rowq);    // wave-uniform -> SGPR
  const int rowel9  = rfq << 9;                            // off/mod af offset (mi=rowq)
  const int rowel10 = rfq << 10;                           // col/final af base
  const int cbase = (rowq << 5) + (quad << 2);             // original-space channel base
  const int tcb   = (rowq << 5) + (quad << 3);             // sigma-space elem base (8 ch)
  const int r0 = (pxq << 5) + nif;                         // ni=0 pixel
  const int r1 = r0 + 16;                                  // ni=1 pixel

  // compressed sF read offsets (ushort elems): addr(ks,ni) = CRni[ks>>1] ^ ((ks&1)<<5)
  int CR0[9], CR1[9];
  #pragma unroll
  for (int kk = 0; kk < 9; kk++) {
    const int dr = kk / 3, dc = kk - dr * 3;
    const int srow = dr * 66 + dc;
    const int sl = (kb + r0 + dc) & 7;          // identical for r1 (16 = 0 mod 8)
    CR0[kk] = ((srow + r0) << 6) + (sl << 3);
    CR1[kk] = ((srow + r1) << 6) + (sl << 3);
  }
  // compressed colT read offsets: addr(khalf,ni) = ctni ^ (khalf<<5)
  const int slE = (kb + r0) & 7;
  const int ct0 = (r0 << 6) + (slE << 3);
  const int ct1 = (r1 << 6) + (slE << 3);
  // colT write offset (ni=0; ni=1 is +1024 elems): slot same for both ni
  const int wslot = ((rowq << 2) + quad + r0) & 7;
  const int wcol0 = (r0 << 6) + (wslot << 3);
  // homT per-ni float bases
  const int hb0 = r0 * 27, hb1 = r1 * 27;

  __syncthreads();

  // ---- off/mod GEMM: wave (rowq,pxq) computes rows rowq*16..+16 of its 32 px ----
  {
    f32x4 acc[2];
    acc[0] = (f32x4){0.f, 0.f, 0.f, 0.f};
    acc[1] = (f32x4){0.f, 0.f, 0.f, 0.f};
    #pragma unroll
    for (int ks = 0; ks < 18; ks++) {
      const int h5 = (ks & 1) << 5, kk = ks >> 1;
      s16x8 af = *(const s16x8*)(Wpk + (ks << 12) + rowel9 + wlaneoff);
      s16x8 b0 = *(const s16x8*)(sF + (CR0[kk] ^ h5));
      s16x8 b1 = *(const s16x8*)(sF + (CR1[kk] ^ h5));
      acc[0] = __builtin_amdgcn_mfma_f32_16x16x32_bf16(af, b0, acc[0], 0, 0, 0);
      acc[1] = __builtin_amdgcn_mfma_f32_16x16x32_bf16(af, b1, acc[1], 0, 0, 0);
    }
    const float4 b4 = *(const float4*)(Bc + (rowq << 4) + (quad << 2));
    const float bb[4] = {b4.x, b4.y, b4.z, b4.w};
    #pragma unroll
    for (int ni = 0; ni < 2; ni++) {
      const int px = ni ? r1 : r0;
      #pragma unroll
      for (int r = 0; r < 4; r++) {
        const int g = (rowq << 4) + (quad << 2) + r;
        float v = acc[ni][r] + bb[r];
        if (g < 18)       homT[px * 27 + g] = v;
        else if (g < 27)  homT[px * 27 + g] = fast_sigmoid(v);
      }
    }
  }

  __syncthreads();   // homT (written by both rowq waves) visible to everyone

  const ushort* xb0 = xtb + ((size_t)b << 20);

  // ---- gather-prefetch state (consumed one iteration later) ----
  float mkv[2];
  float wlv[2][4];
  uint4 gpre[2][4];   // [ni][corner]: 8 contiguous sigma-channels (16B)

  auto prefetch_k = [&](int kk) {
    const int kdr = kk / 3, kdc = kk - kdr * 3;
    #pragma unroll
    for (int ni = 0; ni < 2; ni++) {
      const int px = ni ? r1 : r0;
      const int hb = ni ? hb1 : hb0;
      float ox = homT[hb + kk];
      float oy = homT[hb + 9 + kk];
      mkv[ni] = homT[hb + 18 + kk];
      float px_ = (float)(h + kdr) + ox;
      float py_ = (float)(w0 + px + kdc) + oy;
      float fx = floorf(px_), fy = floorf(py_);
      float qltx = fminf(fmaxf(fx, 0.f), 129.f);
      float qlty = fminf(fmaxf(fy, 0.f), 129.f);
      float qrbx = fminf(fmaxf(fx + 1.f, 0.f), 129.f);
      float qrby = fminf(fmaxf(fy + 1.f, 0.f), 129.f);
      float sx = fminf(fmaxf(px_, 0.f), 129.f);
      float sy = fminf(fmaxf(py_, 0.f), 129.f);
      float ax = 1.f + qltx - sx, bx = 1.f - qrbx + sx;
      float ay = 1.f + qlty - sy, by = 1.f - qrby + sy;
      int iltx = (int)qltx, ilty = (int)qlty, irbx = (int)qrbx, irby = (int)qrby;
      bool vltx = (iltx >= 1) && (iltx <= 128);
      bool vlty = (ilty >= 1) && (ilty <= 128);
      bool vrbx = (irbx >= 1) && (irbx <= 128);
      bool vrby = (irby >= 1) && (irby <= 128);
      float wl[4];
      int   ofs[4];
      wl[0] = (vltx && vlty) ? ax * ay : 0.f;
      wl[1] = (vrbx && vrby) ? bx * by : 0.f;
      wl[2] = (vltx && vrby) ? ax * by : 0.f;
      wl[3] = (vrbx && vlty) ? bx * ay : 0.f;
      ofs[0] = (vltx && vlty) ? ((iltx - 1) << 7) + (ilty - 1) : 0;
      ofs[1] = (vrbx && vrby) ? ((irbx - 1) << 7) + (irby - 1) : 0;
      ofs[2] = (vltx && vrby) ? ((iltx - 1) << 7) + (irby - 1) : 0;
      ofs[3] = (vrbx && vlty) ? ((irbx - 1) << 7) + (ilty - 1) : 0;
      #pragma unroll
      for (int corner = 0; corner < 4; corner++) {
        wlv[ni][corner] = wl[corner];
        gpre[ni][corner] = *(const uint4*)(xb0 + ((size_t)ofs[corner] << 6) + tcb);
      }
    }
  };

  prefetch_k(0);   // loads in flight across col-GEMM(0)

  f32x4 aco[2][2];
  #pragma unroll
  for (int mi = 0; mi < 2; mi++)
    #pragma unroll
    for (int ni = 0; ni < 2; ni++) aco[mi][ni] = (f32x4){0.f, 0.f, 0.f, 0.f};

  s16x8 w2pre[2][2];   // [khalf][mi] final-GEMM fragments, prefetched per k

  #pragma unroll 1
  for (int k = 0; k < 9; k++) {
    // ---- col GEMM for this k: permuted rows 64+k*64 .. 128+k*64 ----
    const int q = 1 + k, og = q >> 1, ocq = q & 1;
    const ushort* wb = Wpk + ((size_t)(((og * 36) + ocq) << 11)) + rowel10 + wlaneoff;
    f32x4 acc[2][2];
    #pragma unroll
    for (int mi = 0; mi < 2; mi++)
      #pragma unroll
      for (int ni = 0; ni < 2; ni++) acc[mi][ni] = (f32x4){0.f, 0.f, 0.f, 0.f};
    __builtin_amdgcn_s_setprio(1);
    #pragma unroll
    for (int ks = 0; ks < 18; ks++) {
      const int h5 = (ks & 1) << 5, kk = ks >> 1;
      const ushort* wp8 = wb + (ks << 12);
      s16x8 af0 = *(const s16x8*)(wp8);
      s16x8 af1 = *(const s16x8*)(wp8 + 512);
      s16x8 b0 = *(const s16x8*)(sF + (CR0[kk] ^ h5));
      s16x8 b1 = *(const s16x8*)(sF + (CR1[kk] ^ h5));
      acc[0][0] = __builtin_amdgcn_mfma_f32_16x16x32_bf16(af0, b0, acc[0][0], 0, 0, 0);
      acc[0][1] = __builtin_amdgcn_mfma_f32_16x16x32_bf16(af0, b1, acc[0][1], 0, 0, 0);
      acc[1][0] = __builtin_amdgcn_mfma_f32_16x16x32_bf16(af1, b0, acc[1][0], 0, 0, 0);
      acc[1][1] = __builtin_amdgcn_mfma_f32_16x16x32_bf16(af1, b1, acc[1][1], 0, 0, 0);
    }
    __builtin_amdgcn_s_setprio(0);

    LDS_BARRIER();   // B1: prior final-MFMA colT ds_reads done before overwrite (WAR)

    // ---- epilogue: tanh + prefetched gather + modulate -> colT (sigma-space) ----
    {
      #pragma unroll
      for (int ni = 0; ni < 2; ni++) {
        const float mk = mkv[ni];
        float pos[2][4];
        #pragma unroll
        for (int mi = 0; mi < 2; mi++)
          #pragma unroll
          for (int r = 0; r < 4; r++) pos[mi][r] = 0.f;
        #pragma unroll
        for (int corner = 0; corner < 4; corner++) {
          uint4 A = gpre[ni][corner];
          float wgt = wlv[ni][corner];
          pos[0][0] += wgt * bflo(A.x); pos[0][1] += wgt * bfhi(A.x);
          pos[0][2] += wgt * bflo(A.y); pos[0][3] += wgt * bfhi(A.y);
          pos[1][0] += wgt * bflo(A.z); pos[1][1] += wgt * bfhi(A.z);
          pos[1][2] += wgt * bflo(A.w); pos[1][3] += wgt * bfhi(A.w);
        }
        float v[2][4];
        #pragma unroll
        for (int mi = 0; mi < 2; mi++) {
          const int c = cbase + mi * 16;
          const float4 b4 = *(const float4*)(Bc + 64 + (k << 6) + c);
          v[mi][0] = (fast_tanh(acc[mi][ni][0] + b4.x) + pos[mi][0]) * mk;
          v[mi][1] = (fast_tanh(acc[mi][ni][1] + b4.y) + pos[mi][1]) * mk;
          v[mi][2] = (fast_tanh(acc[mi][ni][2] + b4.z) + pos[mi][2]) * mk;
          v[mi][3] = (fast_tanh(acc[mi][ni][3] + b4.w) + pos[mi][3]) * mk;
        }
        uint4 ow;
        ow.x = pkbf(v[0][0], v[0][1]);
        ow.y = pkbf(v[0][2], v[0][3]);
        ow.z = pkbf(v[1][0], v[1][1]);
        ow.w = pkbf(v[1][2], v[1][3]);
        *(uint4*)(colT + wcol0 + (ni ? 1024 : 0)) = ow;
      }
    }

    // prefetch final-GEMM weight fragments for THIS k (used right after B2)
    #pragma unroll
    for (int khalf = 0; khalf < 2; khalf++) {
      const ushort* w2 = W2pk + (((k << 1) + khalf) << 11) + rowel10 + wlaneoff;
      w2pre[khalf][0] = *(const s16x8*)(w2);
      w2pre[khalf][1] = *(const s16x8*)(w2 + 512);
    }
    // prefetch gathers for k+1 (complete during final-MFMA(k) + col-GEMM(k+1))
    if (k < 8) prefetch_k(k + 1);

    LDS_BARRIER();   // B2: colT writes visible to final MFMA (RAW); vmcnt NOT drained

    // ---- final-GEMM MFMA: 2 ks-steps over this k-tile ----
    __builtin_amdgcn_s_setprio(1);
    #pragma unroll
    for (int khalf = 0; khalf < 2; khalf++) {
      const int h5 = khalf << 5;
      s16x8 b0 = *(const s16x8*)(colT + (ct0 ^ h5));
      s16x8 b1 = *(const s16x8*)(colT + (ct1 ^ h5));
      aco[0][0] = __builtin_amdgcn_mfma_f32_16x16x32_bf16(w2pre[khalf][0], b0, aco[0][0], 0, 0, 0);
      aco[0][1] = __builtin_amdgcn_mfma_f32_16x16x32_bf16(w2pre[khalf][0], b1, aco[0][1], 0, 0, 0);
      aco[1][0] = __builtin_amdgcn_mfma_f32_16x16x32_bf16(w2pre[khalf][1], b0, aco[1][0], 0, 0, 0);
      aco[1][1] = __builtin_amdgcn_mfma_f32_16x16x32_bf16(w2pre[khalf][1], b1, aco[1][1], 0, 0, 0);
    }
    __builtin_amdgcn_s_setprio(0);
  }

  // ---- store out ----
  #pragma unroll
  for (int mi = 0; mi < 2; mi++) {
    #pragma unroll
    for (int ni = 0; ni < 2; ni++) {
      int hwp = hw0 + (pxq << 5) + ni * 16 + nif;
      #pragma unroll
      for (int r = 0; r < 4; r++) {
        int o = (rowq << 5) + mi * 16 + (quad << 2) + r;
        out[(((size_t)b * 64 + o) << 14) + hwp] = aco[mi][ni][r];
      }
    }
  }
}

extern "C" void kernel_launch(void* const* d_in, const int* in_sizes, int n_in,
                              void* d_out, int out_size, void* d_ws, size_t ws_size,
                              hipStream_t stream) {
  const float* x     = (const float*)d_in[0];
  const float* ref   = (const float*)d_in[1];
  const float* wcd   = (const float*)d_in[2];
  const float* bcd   = (const float*)d_in[3];
  const float* wp    = (const float*)d_in[4];
  const float* bp    = (const float*)d_in[5];
  const float* wm    = (const float*)d_in[6];
  const float* bm    = (const float*)d_in[7];
  const float* wc    = (const float*)d_in[8];
  const float* bc    = (const float*)d_in[9];
  const float* wconv = (const float*)d_in[10];
  float* out = (float*)d_out;

  char* w8 = (char*)d_ws;
  ushort* Wpk     = (ushort*)(w8 + 0);           //    737,280 B
  float*  Bc      = (float*)(w8 + 737280);       //      2,560 B
  ushort* W2pk    = (ushort*)(w8 + 739840);      //     73,728 B
  ushort* fusedt  = (ushort*)(w8 + 813568);      //  8,388,608 B (pixel-major)
  ushort* xtb     = (ushort*)(w8 + 9202176);     //  8,388,608 B -> total 17,590,784 B

  // blocks [0,1024): fused conv + xtb; blocks [1024,2464): weight packing
  k_fused <<<2464, 256, 0, stream>>>(x, ref, wcd, bcd, wp, bp, wm, bm, wc, bc, wconv,
                                     fusedt, xtb, Wpk, Bc, W2pk);
  k_all   <<<1024, 256, 0, stream>>>(Wpk, fusedt, Bc, xtb, W2pk, out);
}

// Round 7
// 231.241 us; speedup vs baseline: 1.1316x; 1.1316x over previous
//
#include <hip/hip_runtime.h>
#include <hip/hip_bf16.h>
#include <math.h>

typedef short s16x8 __attribute__((ext_vector_type(8)));
typedef float f32x4 __attribute__((ext_vector_type(4)));

__device__ inline ushort f2bf(float f) {
  unsigned u = __float_as_uint(f);
  u = (u + 0x7FFF + ((u >> 16) & 1)) >> 16;
  return (ushort)u;
}
__device__ inline float bf2f(ushort u) {
  return __uint_as_float(((unsigned)u) << 16);
}
// packed f32x2 -> bf16x2 RNE (bit-identical to f2bf pair)
__device__ inline unsigned pkbf(float a, float b) {
  __hip_bfloat162 h = __float22bfloat162_rn(make_float2(a, b));
  return *(unsigned*)&h;
}
// bf16 pair unpack from a dword: low half / high half (bit-identical to bf2f)
__device__ inline float bflo(unsigned u) { return __uint_as_float(u << 16); }
__device__ inline float bfhi(unsigned u) { return __uint_as_float(u & 0xffff0000u); }
// fast activations: v_exp_f32 + v_rcp_f32; saturate correctly at +/-inf.
__device__ inline float fast_tanh(float v) {
  float e = __builtin_amdgcn_exp2f(v * 2.8853900817779268f);   // exp(2v)
  return 1.f - 2.f * __builtin_amdgcn_rcpf(e + 1.f);
}
__device__ inline float fast_sigmoid(float v) {
  float e = __builtin_amdgcn_exp2f(v * -1.4426950408889634f);  // exp(-v)
  return __builtin_amdgcn_rcpf(1.f + e);
}

// LDS-only barrier: orders ds ops across waves WITHOUT draining vmcnt (so prefetched
// global loads stay in flight across phase boundaries).
#define LDS_BARRIER()                                          \
  do {                                                         \
    asm volatile("s_waitcnt lgkmcnt(0)" ::: "memory");         \
    __builtin_amdgcn_s_barrier();                              \
  } while (0)

// ---- sigma channel permutation -------------------------------------------------------
// c = [rq m q1 q0 r1 r0] -> sigma(c) = [rq q1 q0 m r1 r0].
// The k_all epilogue thread (rowq,quad) owns channels {rq*32+quad*4+r} U
// {rq*32+16+quad*4+r}; in sigma-space these 8 channels are CONTIGUOUS -> one uint4
// gather per corner. xtb, colT, W2pk live in sigma-space.
__device__ inline int sigma(int c) {
  return (c & 0x20) | ((c & 0x0C) << 1) | ((c & 0x10) >> 2) | (c & 3);
}
__device__ inline int sigma_inv(int d) {
  return (d & 0x20) | ((d & 4) << 2) | ((d & 0x18) >> 1) | (d & 3);
}

// ---- PERMUTED head-row space (640 rows):
//   g in [0,18): off | [18,27): mod | [27,64): pad | [64,640): col j=g-64=k*64+c
//     source col channel cc = c*9+k.
// ---- K1: fused 1x1 conv as MFMA GEMM -> fusedt[pix][64] bf16, xtb (sigma) transpose
//      as a free by-product of B-operand staging, PLUS weight packing (blocks >= 1024).
// GEMM: fused[px][oc] = sum_K A[oc][K] * B[K][px], K = 128 (x-half K-permuted by sigma,
// ref-half natural). Permuting K identically on A and B leaves the contraction
// invariant; the sigma K-order makes the staged B rows IDENTICAL to xtb rows.
// Wpk[og 5][ks 18][ocq 2][mi 4][lane 64][e 8]; W2pk[ks 18][mi 4][lane 64][e 8].
__global__ __launch_bounds__(256) void k_fused(
    const float* __restrict__ x, const float* __restrict__ ref,
    const float* __restrict__ wcd, const float* __restrict__ bcd,
    const float* __restrict__ wp, const float* __restrict__ bp,
    const float* __restrict__ wm, const float* __restrict__ bm,
    const float* __restrict__ wc, const float* __restrict__ bc,
    const float* __restrict__ wconv,
    ushort* __restrict__ fusedt, ushort* __restrict__ xtb,
    ushort* __restrict__ Wpk, float* __restrict__ Bc, ushort* __restrict__ W2pk) {
  __shared__ float sxf[64][68];                       // 17,408 B (pad 68: b128-aligned)
  __shared__ __align__(16) ushort w_lds[64 * 128];    // 16,384 B  A: [oc][16 chunks]
  __shared__ __align__(16) ushort xt_lds[64 * 128];   // 16,384 B  B: [px][16 chunks]
  __shared__ float sb[64];

  if (blockIdx.x >= 1024) {
    // ---- weight-packing blocks (former k_merge), 1440 blocks ----
    int i = (blockIdx.x - 1024) * 256 + threadIdx.x;
    if (i < 368640) {
      int e = i & 7, lane = (i >> 3) & 63, mi = (i >> 9) & 3, ocq = (i >> 11) & 1;
      int hi = i >> 12;                 // 0..89
      int ks = hi % 18, og = hi / 18;
      int g = og * 128 + ocq * 64 + mi * 16 + (lane & 15);
      int ci = ((ks & 1) << 5) + ((lane >> 4) << 3) + e;
      int kk = ks >> 1;
      int col = ci * 9 + kk;
      float v = 0.f;
      if (g < 18)       v = wp[g * 576 + col];
      else if (g < 27)  v = wm[(g - 18) * 576 + col];
      else if (g >= 64) {
        int j = g - 64;
        int cc = (j & 63) * 9 + (j >> 6);
        v = wc[cc * 576 + col];
      }
      Wpk[i] = f2bf(v);
    }
    if (i < 36864) {
      int e = i & 7, lane = (i >> 3) & 63, mi = (i >> 9) & 3, ks = i >> 11;  // 0..17
      int o = mi * 16 + (lane & 15);
      int p = (ks << 5) + ((lane >> 4) << 3) + e;
      int kk2 = p >> 6, d = p & 63;
      int c = sigma_inv(d);            // W2pk K-order lives in sigma-space
      W2pk[i] = f2bf(wconv[o * 576 + c * 9 + kk2]);
    }
    if (i < 640) {
      float bv = 0.f;
      if (i < 18)       bv = bp[i];
      else if (i < 27)  bv = bm[i - 18];
      else if (i >= 64) {
        int j = i - 64;
        bv = bc[(j & 63) * 9 + (j >> 6)];
      }
      Bc[i] = bv;
    }
    return;
  }

  // ---- conv blocks: 64 px each ----
  const int t = threadIdx.x;
  const int b = blockIdx.x >> 8, hw0 = (blockIdx.x & 255) << 6;
  if (t < 64) sb[t] = bcd[t];

  // A-operand: w_lds[oc][chunk g slot-rotated]; g<8 sigma K-order, g>=8 ref natural.
  #pragma unroll
  for (int rep = 0; rep < 4; rep++) {
    int idx = t + (rep << 8);              // 0..1023 = oc*16 + g
    int oc = idx >> 4, g = idx & 15;
    ushort v8[8];
    #pragma unroll
    for (int e = 0; e < 8; e++) {
      int ci = (g < 8) ? sigma_inv((g << 3) + e) : (((g & 7) << 3) + e + 64);
      v8[e] = f2bf(wcd[oc * 128 + ci]);
    }
    *(uint4*)(w_lds + oc * 128 + (((g + oc) & 15) << 3)) = *(uint4*)v8;
  }

  // stage x tile fp32 (coalesced float4)
  #pragma unroll
  for (int rep = 0; rep < 4; rep++) {
    int idx = t + (rep << 8);              // 0..1023 float4s
    int ci = idx >> 4, p4 = (idx & 15) << 2;
    float4 v = *(const float4*)(x + ((size_t)((b << 6) + ci) << 14) + hw0 + p4);
    *(float4*)&sxf[ci][p4] = v;
  }
  __syncthreads();

  // build B x-half (sigma chunks 0..7); rows == xtb rows -> free global transpose
  #pragma unroll
  for (int rep = 0; rep < 2; rep++) {
    int idx = t + (rep << 8);              // 0..511 = px*8 + g
    int px = idx >> 3, g = idx & 7;
    ushort v8[8];
    #pragma unroll
    for (int e = 0; e < 8; e++)
      v8[e] = f2bf(sxf[sigma_inv((g << 3) + e)][px]);
    *(uint4*)(xt_lds + px * 128 + (((g + px) & 15) << 3)) = *(uint4*)v8;
    *(uint4*)(xtb + (((size_t)b << 14) + hw0 + px) * 64 + (g << 3)) = *(uint4*)v8;
  }
  __syncthreads();   // all sxf(x) reads done before overwrite

  // stage ref tile fp32
  #pragma unroll
  for (int rep = 0; rep < 4; rep++) {
    int idx = t + (rep << 8);
    int ci = idx >> 4, p4 = (idx & 15) << 2;
    float4 v = *(const float4*)(ref + ((size_t)((b << 6) + ci) << 14) + hw0 + p4);
    *(float4*)&sxf[ci][p4] = v;
  }
  __syncthreads();

  // build B ref-half (chunks 8..15, natural order)
  #pragma unroll
  for (int rep = 0; rep < 2; rep++) {
    int idx = t + (rep << 8);
    int px = idx >> 3, g = (idx & 7) + 8;
    ushort v8[8];
    #pragma unroll
    for (int e = 0; e < 8; e++)
      v8[e] = f2bf(sxf[((g & 7) << 3) + e][px]);
    *(uint4*)(xt_lds + px * 128 + (((g + px) & 15) << 3)) = *(uint4*)v8;
  }
  __syncthreads();

  // GEMM: wave -> 16 oc, 4 ni x 4 ksteps MFMAs
  const int lane = t & 63, wv4 = t >> 6;
  const int ocl = lane & 15, kb = lane >> 4;
  const int ocr = (wv4 << 4) + ocl;
  f32x4 acc[4];
  #pragma unroll
  for (int ni = 0; ni < 4; ni++) acc[ni] = (f32x4){0.f, 0.f, 0.f, 0.f};
  #pragma unroll
  for (int s = 0; s < 4; s++) {
    const int gA = (s << 2) + kb;
    s16x8 af = *(const s16x8*)(w_lds + ocr * 128 + (((gA + ocr) & 15) << 3));
    #pragma unroll
    for (int ni = 0; ni < 4; ni++) {
      const int px = (ni << 4) + ocl;
      s16x8 bf8 = *(const s16x8*)(xt_lds + px * 128 + (((gA + px) & 15) << 3));
      acc[ni] = __builtin_amdgcn_mfma_f32_16x16x32_bf16(af, bf8, acc[ni], 0, 0, 0);
    }
  }
  // epilogue: +bias, pack bf16, store fusedt[pix][oc]
  const float4 b4 = *(const float4*)&sb[(wv4 << 4) + (kb << 2)];
  #pragma unroll
  for (int ni = 0; ni < 4; ni++) {
    const int px = (ni << 4) + ocl;
    uint2 o;
    o.x = pkbf(acc[ni][0] + b4.x, acc[ni][1] + b4.y);
    o.y = pkbf(acc[ni][2] + b4.z, acc[ni][3] + b4.w);
    *(uint2*)(fusedt + (((size_t)(b << 14) + hw0 + px) << 6) + (wv4 << 4) + (kb << 2)) = o;
  }
}

// ---- K3: FULLY FUSED head-GEMM + sampler + final GEMM, 64-px tiles --------------------
// grid 1024; block 256 = 4 waves; LDS 40,448B -> 4 blocks/CU. (unchanged from round 6)
__global__ __launch_bounds__(256, 4) void k_all(
    const ushort* __restrict__ Wpk, const ushort* __restrict__ fusedt,
    const float* __restrict__ Bc, const ushort* __restrict__ xtb,
    const ushort* __restrict__ W2pk, float* __restrict__ out) {
  __shared__ __align__(16) ushort sF[3 * 66 * 64];    // 25,344 B
  __shared__ __align__(16) ushort colT[64 * 64];      //  8,192 B
  __shared__ float homT[64 * 27];                     //  6,912 B -> 40,448 B total
  const int t = threadIdx.x;
  const int lane = t & 63, wv = t >> 6;
  const int rowid = blockIdx.x;           // b*256 + h*2 + half
  const int b = rowid >> 8;
  const int rem = rowid & 255;
  const int h = rem >> 1, hf = rem & 1;
  const int w0 = hf << 6;
  const int hw0 = (h << 7) + w0;

  // stage fused rows h-1..h+1, w1 in [0,66) covering gw in [w0-1, w0+64]
  for (int idx = t; idx < 1584; idx += 256) {   // 198 pixels x 8 ci-chunks
    int p = idx >> 3, j = idx & 7;
    int row = p / 66, w1 = p - row * 66;
    int gh = h + row - 1, gw = w0 + w1 - 1;
    uint4 v = make_uint4(0u, 0u, 0u, 0u);
    if (gh >= 0 && gh < 128 && (unsigned)gw < 128u)
      v = *(const uint4*)(fusedt + ((size_t)((b << 14) + (gh << 7) + gw) << 6) + j * 8);
    int slot = (j + w1) & 7;
    *(uint4*)(sF + (p << 6) + slot * 8) = v;
  }

  const int pxq = wv & 1, rowq = wv >> 1;
  const int nif = lane & 15, kb = lane >> 4, quad = lane >> 4;
  const int wlaneoff = lane << 3;                          // element offset in weight row
  const int rfq = __builtin_amdgcn_readfirstlane(rowq);    // wave-uniform -> SGPR
  const int rowel9  = rfq << 9;                            // off/mod af offset (mi=rowq)
  const int rowel10 = rfq << 10;                           // col/final af base
  const int cbase = (rowq << 5) + (quad << 2);             // original-space channel base
  const int tcb   = (rowq << 5) + (quad << 3);             // sigma-space elem base (8 ch)
  const int r0 = (pxq << 5) + nif;                         // ni=0 pixel
  const int r1 = r0 + 16;                                  // ni=1 pixel

  // compressed sF read offsets (ushort elems): addr(ks,ni) = CRni[ks>>1] ^ ((ks&1)<<5)
  int CR0[9], CR1[9];
  #pragma unroll
  for (int kk = 0; kk < 9; kk++) {
    const int dr = kk / 3, dc = kk - dr * 3;
    const int srow = dr * 66 + dc;
    const int sl = (kb + r0 + dc) & 7;          // identical for r1 (16 = 0 mod 8)
    CR0[kk] = ((srow + r0) << 6) + (sl << 3);
    CR1[kk] = ((srow + r1) << 6) + (sl << 3);
  }
  // compressed colT read offsets: addr(khalf,ni) = ctni ^ (khalf<<5)
  const int slE = (kb + r0) & 7;
  const int ct0 = (r0 << 6) + (slE << 3);
  const int ct1 = (r1 << 6) + (slE << 3);
  // colT write offset (ni=0; ni=1 is +1024 elems): slot same for both ni
  const int wslot = ((rowq << 2) + quad + r0) & 7;
  const int wcol0 = (r0 << 6) + (wslot << 3);
  // homT per-ni float bases
  const int hb0 = r0 * 27, hb1 = r1 * 27;

  __syncthreads();

  // ---- off/mod GEMM: wave (rowq,pxq) computes rows rowq*16..+16 of its 32 px ----
  {
    f32x4 acc[2];
    acc[0] = (f32x4){0.f, 0.f, 0.f, 0.f};
    acc[1] = (f32x4){0.f, 0.f, 0.f, 0.f};
    #pragma unroll
    for (int ks = 0; ks < 18; ks++) {
      const int h5 = (ks & 1) << 5, kk = ks >> 1;
      s16x8 af = *(const s16x8*)(Wpk + (ks << 12) + rowel9 + wlaneoff);
      s16x8 b0 = *(const s16x8*)(sF + (CR0[kk] ^ h5));
      s16x8 b1 = *(const s16x8*)(sF + (CR1[kk] ^ h5));
      acc[0] = __builtin_amdgcn_mfma_f32_16x16x32_bf16(af, b0, acc[0], 0, 0, 0);
      acc[1] = __builtin_amdgcn_mfma_f32_16x16x32_bf16(af, b1, acc[1], 0, 0, 0);
    }
    const float4 b4 = *(const float4*)(Bc + (rowq << 4) + (quad << 2));
    const float bb[4] = {b4.x, b4.y, b4.z, b4.w};
    #pragma unroll
    for (int ni = 0; ni < 2; ni++) {
      const int px = ni ? r1 : r0;
      #pragma unroll
      for (int r = 0; r < 4; r++) {
        const int g = (rowq << 4) + (quad << 2) + r;
        float v = acc[ni][r] + bb[r];
        if (g < 18)       homT[px * 27 + g] = v;
        else if (g < 27)  homT[px * 27 + g] = fast_sigmoid(v);
      }
    }
  }

  __syncthreads();   // homT (written by both rowq waves) visible to everyone

  const ushort* xb0 = xtb + ((size_t)b << 20);

  // ---- gather-prefetch state (consumed one iteration later) ----
  float mkv[2];
  float wlv[2][4];
  uint4 gpre[2][4];   // [ni][corner]: 8 contiguous sigma-channels (16B)

  auto prefetch_k = [&](int kk) {
    const int kdr = kk / 3, kdc = kk - kdr * 3;
    #pragma unroll
    for (int ni = 0; ni < 2; ni++) {
      const int px = ni ? r1 : r0;
      const int hb = ni ? hb1 : hb0;
      float ox = homT[hb + kk];
      float oy = homT[hb + 9 + kk];
      mkv[ni] = homT[hb + 18 + kk];
      float px_ = (float)(h + kdr) + ox;
      float py_ = (float)(w0 + px + kdc) + oy;
      float fx = floorf(px_), fy = floorf(py_);
      float qltx = fminf(fmaxf(fx, 0.f), 129.f);
      float qlty = fminf(fmaxf(fy, 0.f), 129.f);
      float qrbx = fminf(fmaxf(fx + 1.f, 0.f), 129.f);
      float qrby = fminf(fmaxf(fy + 1.f, 0.f), 129.f);
      float sx = fminf(fmaxf(px_, 0.f), 129.f);
      float sy = fminf(fmaxf(py_, 0.f), 129.f);
      float ax = 1.f + qltx - sx, bx = 1.f - qrbx + sx;
      float ay = 1.f + qlty - sy, by = 1.f - qrby + sy;
      int iltx = (int)qltx, ilty = (int)qlty, irbx = (int)qrbx, irby = (int)qrby;
      bool vltx = (iltx >= 1) && (iltx <= 128);
      bool vlty = (ilty >= 1) && (ilty <= 128);
      bool vrbx = (irbx >= 1) && (irbx <= 128);
      bool vrby = (irby >= 1) && (irby <= 128);
      float wl[4];
      int   ofs[4];
      wl[0] = (vltx && vlty) ? ax * ay : 0.f;
      wl[1] = (vrbx && vrby) ? bx * by : 0.f;
      wl[2] = (vltx && vrby) ? ax * by : 0.f;
      wl[3] = (vrbx && vlty) ? bx * ay : 0.f;
      ofs[0] = (vltx && vlty) ? ((iltx - 1) << 7) + (ilty - 1) : 0;
      ofs[1] = (vrbx && vrby) ? ((irbx - 1) << 7) + (irby - 1) : 0;
      ofs[2] = (vltx && vrby) ? ((iltx - 1) << 7) + (irby - 1) : 0;
      ofs[3] = (vrbx && vlty) ? ((irbx - 1) << 7) + (ilty - 1) : 0;
      #pragma unroll
      for (int corner = 0; corner < 4; corner++) {
        wlv[ni][corner] = wl[corner];
        gpre[ni][corner] = *(const uint4*)(xb0 + ((size_t)ofs[corner] << 6) + tcb);
      }
    }
  };

  prefetch_k(0);   // loads in flight across col-GEMM(0)

  f32x4 aco[2][2];
  #pragma unroll
  for (int mi = 0; mi < 2; mi++)
    #pragma unroll
    for (int ni = 0; ni < 2; ni++) aco[mi][ni] = (f32x4){0.f, 0.f, 0.f, 0.f};

  s16x8 w2pre[2][2];   // [khalf][mi] final-GEMM fragments, prefetched per k

  #pragma unroll 1
  for (int k = 0; k < 9; k++) {
    // ---- col GEMM for this k: permuted rows 64+k*64 .. 128+k*64 ----
    const int q = 1 + k, og = q >> 1, ocq = q & 1;
    const ushort* wb = Wpk + ((size_t)(((og * 36) + ocq) << 11)) + rowel10 + wlaneoff;
    f32x4 acc[2][2];
    #pragma unroll
    for (int mi = 0; mi < 2; mi++)
      #pragma unroll
      for (int ni = 0; ni < 2; ni++) acc[mi][ni] = (f32x4){0.f, 0.f, 0.f, 0.f};
    __builtin_amdgcn_s_setprio(1);
    #pragma unroll
    for (int ks = 0; ks < 18; ks++) {
      const int h5 = (ks & 1) << 5, kk = ks >> 1;
      const ushort* wp8 = wb + (ks << 12);
      s16x8 af0 = *(const s16x8*)(wp8);
      s16x8 af1 = *(const s16x8*)(wp8 + 512);
      s16x8 b0 = *(const s16x8*)(sF + (CR0[kk] ^ h5));
      s16x8 b1 = *(const s16x8*)(sF + (CR1[kk] ^ h5));
      acc[0][0] = __builtin_amdgcn_mfma_f32_16x16x32_bf16(af0, b0, acc[0][0], 0, 0, 0);
      acc[0][1] = __builtin_amdgcn_mfma_f32_16x16x32_bf16(af0, b1, acc[0][1], 0, 0, 0);
      acc[1][0] = __builtin_amdgcn_mfma_f32_16x16x32_bf16(af1, b0, acc[1][0], 0, 0, 0);
      acc[1][1] = __builtin_amdgcn_mfma_f32_16x16x32_bf16(af1, b1, acc[1][1], 0, 0, 0);
    }
    __builtin_amdgcn_s_setprio(0);

    LDS_BARRIER();   // B1: prior final-MFMA colT ds_reads done before overwrite (WAR)

    // ---- epilogue: tanh + prefetched gather + modulate -> colT (sigma-space) ----
    {
      #pragma unroll
      for (int ni = 0; ni < 2; ni++) {
        const float mk = mkv[ni];
        float pos[2][4];
        #pragma unroll
        for (int mi = 0; mi < 2; mi++)
          #pragma unroll
          for (int r = 0; r < 4; r++) pos[mi][r] = 0.f;
        #pragma unroll
        for (int corner = 0; corner < 4; corner++) {
          uint4 A = gpre[ni][corner];
          float wgt = wlv[ni][corner];
          pos[0][0] += wgt * bflo(A.x); pos[0][1] += wgt * bfhi(A.x);
          pos[0][2] += wgt * bflo(A.y); pos[0][3] += wgt * bfhi(A.y);
          pos[1][0] += wgt * bflo(A.z); pos[1][1] += wgt * bfhi(A.z);
          pos[1][2] += wgt * bflo(A.w); pos[1][3] += wgt * bfhi(A.w);
        }
        float v[2][4];
        #pragma unroll
        for (int mi = 0; mi < 2; mi++) {
          const int c = cbase + mi * 16;
          const float4 b4 = *(const float4*)(Bc + 64 + (k << 6) + c);
          v[mi][0] = (fast_tanh(acc[mi][ni][0] + b4.x) + pos[mi][0]) * mk;
          v[mi][1] = (fast_tanh(acc[mi][ni][1] + b4.y) + pos[mi][1]) * mk;
          v[mi][2] = (fast_tanh(acc[mi][ni][2] + b4.z) + pos[mi][2]) * mk;
          v[mi][3] = (fast_tanh(acc[mi][ni][3] + b4.w) + pos[mi][3]) * mk;
        }
        uint4 ow;
        ow.x = pkbf(v[0][0], v[0][1]);
        ow.y = pkbf(v[0][2], v[0][3]);
        ow.z = pkbf(v[1][0], v[1][1]);
        ow.w = pkbf(v[1][2], v[1][3]);
        *(uint4*)(colT + wcol0 + (ni ? 1024 : 0)) = ow;
      }
    }

    // prefetch final-GEMM weight fragments for THIS k (used right after B2)
    #pragma unroll
    for (int khalf = 0; khalf < 2; khalf++) {
      const ushort* w2 = W2pk + (((k << 1) + khalf) << 11) + rowel10 + wlaneoff;
      w2pre[khalf][0] = *(const s16x8*)(w2);
      w2pre[khalf][1] = *(const s16x8*)(w2 + 512);
    }
    // prefetch gathers for k+1 (complete during final-MFMA(k) + col-GEMM(k+1))
    if (k < 8) prefetch_k(k + 1);

    LDS_BARRIER();   // B2: colT writes visible to final MFMA (RAW); vmcnt NOT drained

    // ---- final-GEMM MFMA: 2 ks-steps over this k-tile ----
    __builtin_amdgcn_s_setprio(1);
    #pragma unroll
    for (int khalf = 0; khalf < 2; khalf++) {
      const int h5 = khalf << 5;
      s16x8 b0 = *(const s16x8*)(colT + (ct0 ^ h5));
      s16x8 b1 = *(const s16x8*)(colT + (ct1 ^ h5));
      aco[0][0] = __builtin_amdgcn_mfma_f32_16x16x32_bf16(w2pre[khalf][0], b0, aco[0][0], 0, 0, 0);
      aco[0][1] = __builtin_amdgcn_mfma_f32_16x16x32_bf16(w2pre[khalf][0], b1, aco[0][1], 0, 0, 0);
      aco[1][0] = __builtin_amdgcn_mfma_f32_16x16x32_bf16(w2pre[khalf][1], b0, aco[1][0], 0, 0, 0);
      aco[1][1] = __builtin_amdgcn_mfma_f32_16x16x32_bf16(w2pre[khalf][1], b1, aco[1][1], 0, 0, 0);
    }
    __builtin_amdgcn_s_setprio(0);
  }

  // ---- store out ----
  #pragma unroll
  for (int mi = 0; mi < 2; mi++) {
    #pragma unroll
    for (int ni = 0; ni < 2; ni++) {
      int hwp = hw0 + (pxq << 5) + ni * 16 + nif;
      #pragma unroll
      for (int r = 0; r < 4; r++) {
        int o = (rowq << 5) + mi * 16 + (quad << 2) + r;
        out[(((size_t)b * 64 + o) << 14) + hwp] = aco[mi][ni][r];
      }
    }
  }
}

extern "C" void kernel_launch(void* const* d_in, const int* in_sizes, int n_in,
                              void* d_out, int out_size, void* d_ws, size_t ws_size,
                              hipStream_t stream) {
  const float* x     = (const float*)d_in[0];
  const float* ref   = (const float*)d_in[1];
  const float* wcd   = (const float*)d_in[2];
  const float* bcd   = (const float*)d_in[3];
  const float* wp    = (const float*)d_in[4];
  const float* bp    = (const float*)d_in[5];
  const float* wm    = (const float*)d_in[6];
  const float* bm    = (const float*)d_in[7];
  const float* wc    = (const float*)d_in[8];
  const float* bc    = (const float*)d_in[9];
  const float* wconv = (const float*)d_in[10];
  float* out = (float*)d_out;

  char* w8 = (char*)d_ws;
  ushort* Wpk     = (ushort*)(w8 + 0);           //    737,280 B
  float*  Bc      = (float*)(w8 + 737280);       //      2,560 B
  ushort* W2pk    = (ushort*)(w8 + 739840);      //     73,728 B
  ushort* fusedt  = (ushort*)(w8 + 813568);      //  8,388,608 B (pixel-major)
  ushort* xtb     = (ushort*)(w8 + 9202176);     //  8,388,608 B -> total 17,590,784 B

  // blocks [0,1024): fused conv (MFMA) + xtb; blocks [1024,2464): weight packing
  k_fused <<<2464, 256, 0, stream>>>(x, ref, wcd, bcd, wp, bp, wm, bm, wc, bc, wconv,
                                     fusedt, xtb, Wpk, Bc, W2pk);
  k_all   <<<1024, 256, 0, stream>>>(Wpk, fusedt, Bc, xtb, W2pk, out);
}

// Round 8
// 198.870 us; speedup vs baseline: 1.3157x; 1.1628x over previous
//
#include <hip/hip_runtime.h>
#include <hip/hip_bf16.h>
#include <math.h>

typedef short s16x8 __attribute__((ext_vector_type(8)));
typedef float f32x4 __attribute__((ext_vector_type(4)));

__device__ inline ushort f2bf(float f) {
  unsigned u = __float_as_uint(f);
  u = (u + 0x7FFF + ((u >> 16) & 1)) >> 16;
  return (ushort)u;
}
__device__ inline float bf2f(ushort u) {
  return __uint_as_float(((unsigned)u) << 16);
}
// packed f32x2 -> bf16x2 RNE (bit-identical to f2bf pair)
__device__ inline unsigned pkbf(float a, float b) {
  __hip_bfloat162 h = __float22bfloat162_rn(make_float2(a, b));
  return *(unsigned*)&h;
}
// fast activations: v_exp_f32 + v_rcp_f32; saturate correctly at +/-inf.
__device__ inline float fast_tanh(float v) {
  float e = __builtin_amdgcn_exp2f(v * 2.8853900817779268f);   // exp(2v)
  return 1.f - 2.f * __builtin_amdgcn_rcpf(e + 1.f);
}
__device__ inline float fast_sigmoid(float v) {
  float e = __builtin_amdgcn_exp2f(v * -1.4426950408889634f);  // exp(-v)
  return __builtin_amdgcn_rcpf(1.f + e);
}

// ---- PERMUTED head-row space (640 rows):
//   g in [0,18): off | [18,27): mod | [27,64): pad | [64,640): col j=g-64=k*64+c
//     source col channel cc = c*9+k.
// ---- K1: fused 1x1 conv as MFMA GEMM -> fusedt[pix][64] bf16, xtb (natural order)
//      transpose as a free by-product of B-operand staging, PLUS weight packing
//      (former k_merge) on blocks >= 1024.
// GEMM: fused[px][oc] = sum_K A[oc][K] * B[K][px], K = 128 (x 0..63, ref 64..127).
// Wpk[og 5][ks 18][ocq 2][mi 4][lane 64][e 8]; W2pk[ks 18][mi 4][lane 64][e 8].
__global__ __launch_bounds__(256) void k_fused(
    const float* __restrict__ x, const float* __restrict__ ref,
    const float* __restrict__ wcd, const float* __restrict__ bcd,
    const float* __restrict__ wp, const float* __restrict__ bp,
    const float* __restrict__ wm, const float* __restrict__ bm,
    const float* __restrict__ wc, const float* __restrict__ bc,
    const float* __restrict__ wconv,
    ushort* __restrict__ fusedt, ushort* __restrict__ xtb,
    ushort* __restrict__ Wpk, float* __restrict__ Bc, ushort* __restrict__ W2pk) {
  __shared__ float sxf[64][68];                       // 17,408 B (pad 68: b128-aligned)
  __shared__ __align__(16) ushort w_lds[64 * 128];    // 16,384 B  A: [oc][16 chunks]
  __shared__ __align__(16) ushort xt_lds[64 * 128];   // 16,384 B  B: [px][16 chunks]
  __shared__ float sb[64];

  if (blockIdx.x >= 1024) {
    // ---- weight-packing blocks (former k_merge), 1440 blocks ----
    int i = (blockIdx.x - 1024) * 256 + threadIdx.x;
    if (i < 368640) {
      int e = i & 7, lane = (i >> 3) & 63, mi = (i >> 9) & 3, ocq = (i >> 11) & 1;
      int hi = i >> 12;                 // 0..89
      int ks = hi % 18, og = hi / 18;
      int g = og * 128 + ocq * 64 + mi * 16 + (lane & 15);
      int ci = ((ks & 1) << 5) + ((lane >> 4) << 3) + e;
      int kk = ks >> 1;
      int col = ci * 9 + kk;
      float v = 0.f;
      if (g < 18)       v = wp[g * 576 + col];
      else if (g < 27)  v = wm[(g - 18) * 576 + col];
      else if (g >= 64) {
        int j = g - 64;
        int cc = (j & 63) * 9 + (j >> 6);
        v = wc[cc * 576 + col];
      }
      Wpk[i] = f2bf(v);
    }
    if (i < 36864) {
      int e = i & 7, lane = (i >> 3) & 63, mi = (i >> 9) & 3, ks = i >> 11;  // 0..17
      int o = mi * 16 + (lane & 15);
      int p = (ks << 5) + ((lane >> 4) << 3) + e;
      int kk2 = p >> 6, c = p & 63;
      W2pk[i] = f2bf(wconv[o * 576 + c * 9 + kk2]);
    }
    if (i < 640) {
      float bv = 0.f;
      if (i < 18)       bv = bp[i];
      else if (i < 27)  bv = bm[i - 18];
      else if (i >= 64) {
        int j = i - 64;
        bv = bc[(j & 63) * 9 + (j >> 6)];
      }
      Bc[i] = bv;
    }
    return;
  }

  // ---- conv blocks: 64 px each ----
  const int t = threadIdx.x;
  const int b = blockIdx.x >> 8, hw0 = (blockIdx.x & 255) << 6;
  if (t < 64) sb[t] = bcd[t];

  // A-operand: w_lds[oc][chunk g slot-rotated], natural K-order (ci = g*8+e).
  #pragma unroll
  for (int rep = 0; rep < 4; rep++) {
    int idx = t + (rep << 8);              // 0..1023 = oc*16 + g
    int oc = idx >> 4, g = idx & 15;
    ushort v8[8];
    #pragma unroll
    for (int e = 0; e < 8; e++)
      v8[e] = f2bf(wcd[oc * 128 + (g << 3) + e]);
    *(uint4*)(w_lds + oc * 128 + (((g + oc) & 15) << 3)) = *(uint4*)v8;
  }

  // stage x tile fp32 (coalesced float4)
  #pragma unroll
  for (int rep = 0; rep < 4; rep++) {
    int idx = t + (rep << 8);              // 0..1023 float4s
    int ci = idx >> 4, p4 = (idx & 15) << 2;
    float4 v = *(const float4*)(x + ((size_t)((b << 6) + ci) << 14) + hw0 + p4);
    *(float4*)&sxf[ci][p4] = v;
  }
  __syncthreads();

  // build B x-half (chunks 0..7, natural); rows == xtb rows -> free global transpose
  #pragma unroll
  for (int rep = 0; rep < 2; rep++) {
    int idx = t + (rep << 8);              // 0..511 = px*8 + g
    int px = idx >> 3, g = idx & 7;
    ushort v8[8];
    #pragma unroll
    for (int e = 0; e < 8; e++)
      v8[e] = f2bf(sxf[(g << 3) + e][px]);
    *(uint4*)(xt_lds + px * 128 + (((g + px) & 15) << 3)) = *(uint4*)v8;
    *(uint4*)(xtb + (((size_t)b << 14) + hw0 + px) * 64 + (g << 3)) = *(uint4*)v8;
  }
  __syncthreads();   // all sxf(x) reads done before overwrite

  // stage ref tile fp32
  #pragma unroll
  for (int rep = 0; rep < 4; rep++) {
    int idx = t + (rep << 8);
    int ci = idx >> 4, p4 = (idx & 15) << 2;
    float4 v = *(const float4*)(ref + ((size_t)((b << 6) + ci) << 14) + hw0 + p4);
    *(float4*)&sxf[ci][p4] = v;
  }
  __syncthreads();

  // build B ref-half (chunks 8..15, natural)
  #pragma unroll
  for (int rep = 0; rep < 2; rep++) {
    int idx = t + (rep << 8);
    int px = idx >> 3, g = (idx & 7) + 8;
    ushort v8[8];
    #pragma unroll
    for (int e = 0; e < 8; e++)
      v8[e] = f2bf(sxf[((g & 7) << 3) + e][px]);
    *(uint4*)(xt_lds + px * 128 + (((g + px) & 15) << 3)) = *(uint4*)v8;
  }
  __syncthreads();

  // GEMM: wave -> 16 oc, 4 ni x 4 ksteps MFMAs
  const int lane = t & 63, wv4 = t >> 6;
  const int ocl = lane & 15, kb = lane >> 4;
  const int ocr = (wv4 << 4) + ocl;
  f32x4 acc[4];
  #pragma unroll
  for (int ni = 0; ni < 4; ni++) acc[ni] = (f32x4){0.f, 0.f, 0.f, 0.f};
  #pragma unroll
  for (int s = 0; s < 4; s++) {
    const int gA = (s << 2) + kb;
    s16x8 af = *(const s16x8*)(w_lds + ocr * 128 + (((gA + ocr) & 15) << 3));
    #pragma unroll
    for (int ni = 0; ni < 4; ni++) {
      const int px = (ni << 4) + ocl;
      s16x8 bf8 = *(const s16x8*)(xt_lds + px * 128 + (((gA + px) & 15) << 3));
      acc[ni] = __builtin_amdgcn_mfma_f32_16x16x32_bf16(af, bf8, acc[ni], 0, 0, 0);
    }
  }
  // epilogue: +bias, pack bf16, store fusedt[pix][oc]
  const float4 b4 = *(const float4*)&sb[(wv4 << 4) + (kb << 2)];
  #pragma unroll
  for (int ni = 0; ni < 4; ni++) {
    const int px = (ni << 4) + ocl;
    uint2 o;
    o.x = pkbf(acc[ni][0] + b4.x, acc[ni][1] + b4.y);
    o.y = pkbf(acc[ni][2] + b4.z, acc[ni][3] + b4.w);
    *(uint2*)(fusedt + (((size_t)(b << 14) + hw0 + px) << 6) + (wv4 << 4) + (kb << 2)) = o;
  }
}

// ---- K3: FULLY FUSED head-GEMM + sampler + final GEMM, 64-px tiles --------------------
// RESTORED round-0 structure verbatim (measured 115 us, FETCH 41 MB, no scratch).
// Rounds 1-7 k_all restructures (prefetch arrays, fused epilogue) pushed live state to
// ~120 VGPR vs 64 allocated -> remat/scratch on the critical path; all landed 132-134 us.
// grid 1024; block 256 = 4 waves; 4 blocks/CU (LDS 40,448B).
// Wave roles: pxq = wv&1 (32 px), rowq = wv>>1 (32 GEMM rows / 32 out-oc).
__global__ __launch_bounds__(256) void k_all(
    const ushort* __restrict__ Wpk, const ushort* __restrict__ fusedt,
    const float* __restrict__ Bc, const ushort* __restrict__ xtb,
    const ushort* __restrict__ W2pk, float* __restrict__ out) {
  __shared__ __align__(16) ushort sF[3 * 66 * 64];    // 25,344 B
  __shared__ __align__(16) ushort colT[64 * 64];      //  8,192 B
  __shared__ float homT[64 * 27];                     //  6,912 B
  const int t = threadIdx.x;
  const int lane = t & 63, wv = t >> 6;
  const int rowid = blockIdx.x;           // b*256 + h*2 + half
  const int b = rowid >> 8;
  const int rem = rowid & 255;
  const int h = rem >> 1, hf = rem & 1;
  const int w0 = hf << 6;
  const int hw0 = (h << 7) + w0;

  // stage fused rows h-1..h+1, w1 in [0,66) covering gw in [w0-1, w0+64]
  for (int idx = t; idx < 1584; idx += 256) {   // 198 pixels x 8 ci-chunks
    int p = idx >> 3, j = idx & 7;
    int row = p / 66, w1 = p - row * 66;
    int gh = h + row - 1, gw = w0 + w1 - 1;
    uint4 v = make_uint4(0u, 0u, 0u, 0u);
    if (gh >= 0 && gh < 128 && (unsigned)gw < 128u)
      v = *(const uint4*)(fusedt + ((size_t)((b << 14) + (gh << 7) + gw) << 6) + j * 8);
    int slot = (j + w1) & 7;
    *(uint4*)(sF + (p << 6) + slot * 8) = v;
  }
  __syncthreads();

  const int pxq = wv & 1, rowq = wv >> 1;
  const int nif = lane & 15, kb = lane >> 4, quad = lane >> 4;

  // ---- off/mod GEMM: permuted rows 0..31 (rowq==0 waves only) ----
  if (rowq == 0) {
    f32x4 acc[2][2];
    #pragma unroll
    for (int mi = 0; mi < 2; mi++)
      #pragma unroll
      for (int ni = 0; ni < 2; ni++) acc[mi][ni] = (f32x4){0.f, 0.f, 0.f, 0.f};
    #pragma unroll 2
    for (int ks = 0; ks < 18; ks++) {
      const int kk = ks >> 1, half = ks & 1;
      const int dr = kk / 3, dc = kk - dr * 3;
      const ushort* wp8 = Wpk + ((size_t)(ks << 12)) + (lane << 3);  // og=0, ocq=0
      s16x8 af[2], bfr[2];
      #pragma unroll
      for (int mi = 0; mi < 2; mi++)
        af[mi] = *(const s16x8*)(wp8 + (mi << 9));
      const int gci = half * 4 + kb;
      #pragma unroll
      for (int ni = 0; ni < 2; ni++) {
        int r = (pxq << 5) + ni * 16 + nif;
        int w1 = r + dc;
        int slot = (gci + w1) & 7;
        bfr[ni] = *(const s16x8*)(sF + ((dr * 66 + w1) << 6) + slot * 8);
      }
      #pragma unroll
      for (int mi = 0; mi < 2; mi++)
        #pragma unroll
        for (int ni = 0; ni < 2; ni++)
          acc[mi][ni] = __builtin_amdgcn_mfma_f32_16x16x32_bf16(af[mi], bfr[ni], acc[mi][ni], 0, 0, 0);
    }
    #pragma unroll
    for (int mi = 0; mi < 2; mi++) {
      #pragma unroll
      for (int ni = 0; ni < 2; ni++) {
        int px = (pxq << 5) + ni * 16 + nif;
        #pragma unroll
        for (int r = 0; r < 4; r++) {
          int g = mi * 16 + (quad << 2) + r;
          float v = acc[mi][ni][r] + Bc[g];
          if (g < 18)       homT[px * 27 + g] = v;
          else if (g < 27)  homT[px * 27 + g] = fast_sigmoid(v);
        }
      }
    }
  }

  // sampler per-pixel identity: 4 thr/px x 16 ch
  const int cq = t >> 6, pxl = t & 63, c0 = cq << 4;
  const int ww = w0 + pxl;
  const ushort* xb = xtb + ((size_t)b << 20);

  f32x4 aco[2][2];
  #pragma unroll
  for (int mi = 0; mi < 2; mi++)
    #pragma unroll
    for (int ni = 0; ni < 2; ni++) aco[mi][ni] = (f32x4){0.f, 0.f, 0.f, 0.f};

  #pragma unroll 1
  for (int k = 0; k < 9; k++) {
    // ---- col GEMM for this k: permuted rows 64+k*64 .. 128+k*64 ----
    const int q = 1 + k, og = q >> 1, ocq = q & 1;
    f32x4 acc[2][2];
    #pragma unroll
    for (int mi = 0; mi < 2; mi++)
      #pragma unroll
      for (int ni = 0; ni < 2; ni++) acc[mi][ni] = (f32x4){0.f, 0.f, 0.f, 0.f};
    #pragma unroll 2
    for (int ks = 0; ks < 18; ks++) {
      const int kk = ks >> 1, half = ks & 1;
      const int dr = kk / 3, dc = kk - dr * 3;
      const ushort* wp8 = Wpk + ((size_t)((((og * 18 + ks) << 1) + ocq) << 11)) + (lane << 3);
      s16x8 af[2], bfr[2];
      #pragma unroll
      for (int mi = 0; mi < 2; mi++)
        af[mi] = *(const s16x8*)(wp8 + (((rowq << 1) + mi) << 9));
      const int gci = half * 4 + kb;
      #pragma unroll
      for (int ni = 0; ni < 2; ni++) {
        int r = (pxq << 5) + ni * 16 + nif;
        int w1 = r + dc;
        int slot = (gci + w1) & 7;
        bfr[ni] = *(const s16x8*)(sF + ((dr * 66 + w1) << 6) + slot * 8);
      }
      #pragma unroll
      for (int mi = 0; mi < 2; mi++)
        #pragma unroll
        for (int ni = 0; ni < 2; ni++)
          acc[mi][ni] = __builtin_amdgcn_mfma_f32_16x16x32_bf16(af[mi], bfr[ni], acc[mi][ni], 0, 0, 0);
    }
    __syncthreads();   // prior k's finalMFMA reads of colT complete (k=0: homT visible)

    // epilogue: tanh -> colT (slot-rotated)
    #pragma unroll
    for (int mi = 0; mi < 2; mi++) {
      #pragma unroll
      for (int ni = 0; ni < 2; ni++) {
        int px = (pxq << 5) + ni * 16 + nif;
        int c = (rowq << 5) + mi * 16 + (quad << 2);
        float4 b4 = *(const float4*)(Bc + 64 + (k << 6) + c);
        ushort v4[4];
        v4[0] = f2bf(fast_tanh(acc[mi][ni][0] + b4.x));
        v4[1] = f2bf(fast_tanh(acc[mi][ni][1] + b4.y));
        v4[2] = f2bf(fast_tanh(acc[mi][ni][2] + b4.z));
        v4[3] = f2bf(fast_tanh(acc[mi][ni][3] + b4.w));
        int slot = ((c >> 3) + px) & 7;
        *(uint2*)(colT + (px << 6) + slot * 8 + (c & 7)) = *(uint2*)v4;
      }
    }
    __syncthreads();   // colT visible to sampler

    // ---- sampler: 16 channels of pixel pxl, in-place update of colT ----
    {
      float ox = homT[pxl * 27 + k];
      float oy = homT[pxl * 27 + 9 + k];
      float mk = homT[pxl * 27 + 18 + k];
      float px_ = (float)(h + k / 3) + ox;
      float py_ = (float)(ww + k % 3) + oy;
      float fx = floorf(px_), fy = floorf(py_);
      float qltx = fminf(fmaxf(fx, 0.f), 129.f);
      float qlty = fminf(fmaxf(fy, 0.f), 129.f);
      float qrbx = fminf(fmaxf(fx + 1.f, 0.f), 129.f);
      float qrby = fminf(fmaxf(fy + 1.f, 0.f), 129.f);
      float sx = fminf(fmaxf(px_, 0.f), 129.f);
      float sy = fminf(fmaxf(py_, 0.f), 129.f);
      float ax = 1.f + qltx - sx, bx = 1.f - qrbx + sx;
      float ay = 1.f + qlty - sy, by = 1.f - qrby + sy;
      int iltx = (int)qltx, ilty = (int)qlty, irbx = (int)qrbx, irby = (int)qrby;
      bool vltx = (iltx >= 1) && (iltx <= 128);
      bool vlty = (ilty >= 1) && (ilty <= 128);
      bool vrbx = (irbx >= 1) && (irbx <= 128);
      bool vrby = (irby >= 1) && (irby <= 128);
      float wl[4];
      int   ofs[4];
      wl[0] = (vltx && vlty) ? ax * ay : 0.f;
      wl[1] = (vrbx && vrby) ? bx * by : 0.f;
      wl[2] = (vltx && vrby) ? ax * by : 0.f;
      wl[3] = (vrbx && vlty) ? bx * ay : 0.f;
      ofs[0] = (vltx && vlty) ? ((iltx - 1) << 7) + (ilty - 1) : 0;
      ofs[1] = (vrbx && vrby) ? ((irbx - 1) << 7) + (irby - 1) : 0;
      ofs[2] = (vltx && vrby) ? ((iltx - 1) << 7) + (irby - 1) : 0;
      ofs[3] = (vrbx && vlty) ? ((irbx - 1) << 7) + (ilty - 1) : 0;

      float pos[16];
      #pragma unroll
      for (int j = 0; j < 16; j++) pos[j] = 0.f;
      #pragma unroll
      for (int corner = 0; corner < 4; corner++) {
        const ushort* p = xb + ((size_t)ofs[corner] << 6) + c0;
        float wgt = wl[corner];
        ushort tmp[16];
        *(uint4*)(tmp)     = *(const uint4*)(p);
        *(uint4*)(tmp + 8) = *(const uint4*)(p + 8);
        #pragma unroll
        for (int j = 0; j < 16; j++) pos[j] += wgt * bf2f(tmp[j]);
      }
      // read own col slots, update, write back (thread-exclusive -> no barrier)
      #pragma unroll
      for (int q2 = 0; q2 < 2; q2++) {
        int chunk = (cq << 1) + q2;
        int slot = (chunk + pxl) & 7;
        ushort* cp = colT + (pxl << 6) + slot * 8;
        ushort ct[8];
        *(uint4*)ct = *(const uint4*)cp;
        #pragma unroll
        for (int j = 0; j < 8; j++)
          ct[j] = f2bf((bf2f(ct[j]) + pos[q2 * 8 + j]) * mk);
        *(uint4*)cp = *(uint4*)ct;
      }
    }
    __syncthreads();   // updated colT visible to MFMA

    // ---- final-GEMM MFMA: 2 ks-steps over this k-tile ----
    #pragma unroll
    for (int khalf = 0; khalf < 2; khalf++) {
      int ks2 = (k << 1) + khalf;
      s16x8 af[2], bfr[2];
      #pragma unroll
      for (int mi = 0; mi < 2; mi++)
        af[mi] = *(const s16x8*)(W2pk + ((((ks2 << 2) + (rowq << 1) + mi) << 6) + lane) * 8);
      const int g0 = (khalf << 2) + kb;
      #pragma unroll
      for (int ni = 0; ni < 2; ni++) {
        int r = (pxq << 5) + ni * 16 + nif;
        int slot = (g0 + r) & 7;
        bfr[ni] = *(const s16x8*)(colT + (r << 6) + slot * 8);
      }
      #pragma unroll
      for (int mi = 0; mi < 2; mi++)
        #pragma unroll
        for (int ni = 0; ni < 2; ni++)
          aco[mi][ni] = __builtin_amdgcn_mfma_f32_16x16x32_bf16(af[mi], bfr[ni], aco[mi][ni], 0, 0, 0);
    }
  }

  // ---- store out ----
  #pragma unroll
  for (int mi = 0; mi < 2; mi++) {
    #pragma unroll
    for (int ni = 0; ni < 2; ni++) {
      int hwp = hw0 + (pxq << 5) + ni * 16 + nif;
      #pragma unroll
      for (int r = 0; r < 4; r++) {
        int o = (rowq << 5) + mi * 16 + (quad << 2) + r;
        out[(((size_t)b * 64 + o) << 14) + hwp] = aco[mi][ni][r];
      }
    }
  }
}

extern "C" void kernel_launch(void* const* d_in, const int* in_sizes, int n_in,
                              void* d_out, int out_size, void* d_ws, size_t ws_size,
                              hipStream_t stream) {
  const float* x     = (const float*)d_in[0];
  const float* ref   = (const float*)d_in[1];
  const float* wcd   = (const float*)d_in[2];
  const float* bcd   = (const float*)d_in[3];
  const float* wp    = (const float*)d_in[4];
  const float* bp    = (const float*)d_in[5];
  const float* wm    = (const float*)d_in[6];
  const float* bm    = (const float*)d_in[7];
  const float* wc    = (const float*)d_in[8];
  const float* bc    = (const float*)d_in[9];
  const float* wconv = (const float*)d_in[10];
  float* out = (float*)d_out;

  char* w8 = (char*)d_ws;
  ushort* Wpk     = (ushort*)(w8 + 0);           //    737,280 B
  float*  Bc      = (float*)(w8 + 737280);       //      2,560 B
  ushort* W2pk    = (ushort*)(w8 + 739840);      //     73,728 B
  ushort* fusedt  = (ushort*)(w8 + 813568);      //  8,388,608 B (pixel-major)
  ushort* xtb     = (ushort*)(w8 + 9202176);     //  8,388,608 B -> total 17,590,784 B

  // blocks [0,1024): fused conv (MFMA) + xtb; blocks [1024,2464): weight packing
  k_fused <<<2464, 256, 0, stream>>>(x, ref, wcd, bcd, wp, bp, wm, bm, wc, bc, wconv,
                                     fusedt, xtb, Wpk, Bc, W2pk);
  k_all   <<<1024, 256, 0, stream>>>(Wpk, fusedt, Bc, xtb, W2pk, out);
}